// Round 3
// baseline (166.623 us; speedup 1.0000x reference)
//
#include <hip/hip_runtime.h>

typedef __fp16 h2 __attribute__((ext_vector_type(2)));

constexpr int VIEWS = 360;
constexpr int IMGSZ = 512;
constexpr int WCHUNK = 64;   // w per block
constexpr int KH = 64;       // h per LDS chunk (== wave size, required by mapping B)
constexpr int MAXNY = 94;    // max staged rows
constexpr int LDSDW = 9800;  // tile dwords = 39200 B -> 4 blocks/CU
constexpr int PW = 712;      // padded width (dword positions per row)
constexpr int PH = 704;      // padded height
constexpr int PAD = 96;

// Async global->LDS 16B copy. LDS dest = wave-uniform base + lane*16;
// global src is per-lane.
#define ASYNC_CP16(SRC, DST)                                              \
    __builtin_amdgcn_global_load_lds(                                     \
        (const __attribute__((address_space(1))) unsigned*)(SRC),         \
        (__attribute__((address_space(3))) unsigned*)(DST), 16, 0, 0)

// ---------- pad kernel: zero-padded, BATCH-PACKED f16 texels ---------------
__global__ __launch_bounds__(256) void pad_kernel(const float* __restrict__ x,
                                                  unsigned* __restrict__ padq) {
    constexpr int PW4 = PW / 4;              // 178 groups per row
    constexpr int total = PH * PW4;          // 125312 groups
    int idx = blockIdx.x * 256 + threadIdx.x;
    if (idx >= total) return;
    int py = idx / PW4;
    int px4 = idx - py * PW4;
    int gx = px4 * 4 - PAD;
    int gy = py - PAD;
    const float* img0 = x;
    const float* img1 = x + (size_t)IMGSZ * IMGSZ;
    float4 a = make_float4(0.f, 0.f, 0.f, 0.f);
    float4 bq = a;
    if ((unsigned)gy < (unsigned)IMGSZ && (unsigned)gx < (unsigned)IMGSZ) {
        size_t off = (size_t)gy * IMGSZ + gx;
        a  = *(const float4*)(img0 + off);
        bq = *(const float4*)(img1 + off);
    }
    uint4 d;
    d.x = __builtin_bit_cast(unsigned, __builtin_amdgcn_cvt_pkrtz(a.x, bq.x));
    d.y = __builtin_bit_cast(unsigned, __builtin_amdgcn_cvt_pkrtz(a.y, bq.y));
    d.z = __builtin_bit_cast(unsigned, __builtin_amdgcn_cvt_pkrtz(a.z, bq.z));
    d.w = __builtin_bit_cast(unsigned, __builtin_amdgcn_cvt_pkrtz(a.w, bq.w));
    *(uint4*)&padq[(size_t)idx * 4] = d;
}

// Conflict cost estimate for per-lane dword stride d (wave64 over 32 banks).
// Odd rounded stride => bank-bijective (free). 2-way is free on CDNA4 (m136).
__device__ __forceinline__ float conflict_score(float d) {
    float ad = fabsf(d);
    float m = ad - 32.0f * floorf(ad * 0.03125f);   // ad mod 32
    float r = rintf(m);
    float eta = fabsf(m - r);                       // fractional jitter
    int ri = ((int)r) & 31;
    float base;
    if (ri & 1)       base = 0.0f;                  // odd: conflict-free
    else if (ri == 0) base = (ad < 0.5f) ? 0.6f : 8.0f; // broadcast ok; 32k bad
    else if (ri & 2)  base = 1.0f;                  // 2 mod 4: ~2-way (cheap)
    else if (ri & 4)  base = 2.2f;                  // 4-way
    else if (ri & 8)  base = 4.0f;                  // 8-way
    else              base = 6.0f;                  // 16-way
    return base * fmaxf(0.0f, 1.0f - 4.0f * eta);   // jitter spreads banks
}

// Safe h-interval bound for constraint  -1 < coef*h + base < 512  where base
// varies linearly over [ba..bb] (two w endpoints). Union over w (conservative).
__device__ __forceinline__ void cons_bounds(float coef, float ba, float bb,
                                            float& lo, float& hi) {
    if (fabsf(coef) > 1e-6f) {
        float la = (-1.0f - ba) / coef, ha = (512.0f - ba) / coef;
        float lb = (-1.0f - bb) / coef, hb = (512.0f - bb) / coef;
        lo = fminf(fminf(la, ha), fminf(lb, hb));
        hi = fmaxf(fmaxf(la, ha), fmaxf(lb, hb));
    } else {
        bool ina = (ba > -1.0f) && (ba < 512.0f);
        bool inb = (bb > -1.0f) && (bb < 512.0f);
        if (!ina && !inb && ((ba <= -1.0f) == (bb <= -1.0f))) {
            lo = 1e30f; hi = -1e30f;                // empty for every w
        } else {
            lo = -1e30f; hi = 1e30f;                // h unconstrained
        }
    }
}

// ---------- main kernel: dual-mapping gather, view-adaptive (mode, P) ------
__global__ __launch_bounds__(256) void fp_kernel(const unsigned* __restrict__ padq,
                                                 float* __restrict__ out) {
    __shared__ __align__(16) unsigned tileU[LDSDW];

    int blk = blockIdx.x;          // 2880 = VIEWS * 8
    int wc = blk & 7;
    int v = blk >> 3;

    int tid = threadIdx.x;
    int lane = tid & 63;
    int g = tid >> 6;              // wave id 0..3
    int w = wc * WCHUNK + lane;    // mapping-A output column

    double ang = -3.14159265358979323846 * (double)(v + 1) / (double)VIEWS
                 - 3.14159265358979323846;
    float c = (float)cos(ang);
    float s = (float)sin(ang);

    // ---- per-view (mode, pitch) selection --------------------------------
    // Mapping A (lane=w, loop h): per-lane read stride = c + P*s.
    // Mapping B (lane=h, loop w): per-lane read stride = c*P - s.
    // Verticals (s~1) need B; horizontals (c~+-1) need A; diagonals tune P.
    float as_ = fabsf(s), ac_ = fabsf(c);
    int sxi = (int)(63.0f * (as_ + ac_)) + 6;     // extent bound (x and y)
    int NYbb = min(sxi, MAXNY);
    int bestP = 100, bestMode = 0;
    float bestSc = conflict_score(c + 100.0f * s);  // always-feasible default
    {
        float sB0 = conflict_score(c * 100.0f - s) + 0.25f;
        if (sB0 < bestSc) { bestSc = sB0; bestMode = 1; }
    }
    #pragma unroll
    for (int pi = 0; pi < 5; ++pi) {
        int P = 96 + 4 * pi;
        if (P == 100) continue;                    // already scored
        if (P < sxi + 2) continue;                 // must cover x-extent
        if (P * NYbb > LDSDW) continue;            // LDS footprint cap
        float fP = (float)P;
        float sA = conflict_score(c + fP * s) + 0.02f * (float)pi;
        float sB = conflict_score(c * fP - s) + 0.02f * (float)pi + 0.25f;
        if (sA < bestSc) { bestSc = sA; bestP = P; bestMode = 0; }
        if (sB < bestSc) { bestSc = sB; bestP = P; bestMode = 1; }
    }
    int P = bestP;
    int mode = bestMode;
    int NXW = P >> 2;                              // staged 16B groups per row
    unsigned mgc = (262144u + (unsigned)NXW - 1u) / (unsigned)NXW; // exact div
    int stepRow = PW - P;
    int NYcap = min(MAXNY, LDSDW / P);

    float xw = (float)w + 0.5f - 256.0f;
    float cxw = fmaf(c, xw, 255.5f);
    float sxw = fmaf(s, xw, 255.5f);

    float xa = (float)(wc * WCHUNK) + 0.5f - 256.0f;
    float xb = xa + 63.0f;

    int bh0, bh1;
    int wh0 = 0, wh1 = -1;         // mapping-B per-wave h bounds
    if (mode == 0) {
        // ---- A: per-thread valid-h interval (validated rounds 2-11) ------
        float lo = -1e30f, hi = 1e30f;
        {
            float coef = -s, base = cxw;
            if (fabsf(coef) > 1e-6f) {
                float a = (-1.0f - base) / coef;
                float bq = (512.0f - base) / coef;
                lo = fmaxf(lo, fminf(a, bq));
                hi = fminf(hi, fmaxf(a, bq));
            } else if (!(base > -1.0f && base < 512.0f)) {
                lo = 1e30f; hi = -1e30f;
            }
        }
        {
            float coef = c, base = sxw;
            if (fabsf(coef) > 1e-6f) {
                float a = (-1.0f - base) / coef;
                float bq = (512.0f - base) / coef;
                lo = fmaxf(lo, fminf(a, bq));
                hi = fminf(hi, fmaxf(a, bq));
            } else if (!(base > -1.0f && base < 512.0f)) {
                lo = 1e30f; hi = -1e30f;
            }
        }
        float h0f = fminf(fmaxf(floorf(lo + 255.5f) - 1.0f, 0.0f), 512.0f);
        float h1f = fminf(fmaxf(ceilf(hi + 255.5f) + 1.0f, -1.0f), 511.0f);
        int h0 = (int)h0f;
        int h1 = (int)h1f;
        bh0 = h0; bh1 = h1;
        #pragma unroll
        for (int m = 1; m < 64; m <<= 1) {
            bh0 = min(bh0, __shfl_xor(bh0, m, 64));
            bh1 = max(bh1, __shfl_xor(bh1, m, 64));
        }
    } else {
        // ---- B: analytic per-wave bounds; block bounds via LDS union -----
        float xwa = (float)(wc * WCHUNK + (g << 4)) + 0.5f - 256.0f;
        float xwb = xwa + 15.0f;
        float lo1, hi1, lo2, hi2;
        cons_bounds(-s, fmaf(c, xwa, 255.5f), fmaf(c, xwb, 255.5f), lo1, hi1);
        cons_bounds(c,  fmaf(s, xwa, 255.5f), fmaf(s, xwb, 255.5f), lo2, hi2);
        float wlo = fmaxf(lo1, lo2), whi = fminf(hi1, hi2);
        wh0 = (int)fminf(fmaxf(floorf(wlo + 255.5f) - 1.0f, 0.0f), 512.0f);
        wh1 = (int)fminf(fmaxf(ceilf(whi + 255.5f) + 1.0f, -1.0f), 511.0f);
        if (lane == 0) {
            tileU[(g << 1)] = (unsigned)(wh0 + 1024);
            tileU[(g << 1) + 1] = (unsigned)(wh1 + 1024);
        }
        __syncthreads();
        int b0 = 1 << 30, b1 = -(1 << 30);
        #pragma unroll
        for (int q2 = 0; q2 < 4; ++q2) {
            b0 = min(b0, (int)tileU[(q2 << 1)] - 1024);
            b1 = max(b1, (int)tileU[(q2 << 1) + 1] - 1024);
        }
        bh0 = b0; bh1 = b1;
        __syncthreads();
    }

    float acc0 = 0.0f, acc1 = 0.0f;        // mapping-A accumulators
    h2 accB[16];                            // mapping-B accumulators (per w)
    #pragma unroll
    for (int j = 0; j < 16; ++j) accB[j] = (h2)0.0f;
    float step4x = -4.0f * s;
    float step4y = 4.0f * c;

    for (int hc = bh0; hc <= bh1; hc += KH) {
        int hend = min(hc + KH - 1, bh1);

        float ha = (float)hc - 255.5f;
        float hb = (float)hend - 255.5f;
        float ix00 = c * xa - s * ha, ix01 = c * xa - s * hb;
        float ix10 = c * xb - s * ha, ix11 = c * xb - s * hb;
        float iy00 = s * xa + c * ha, iy01 = s * xa + c * hb;
        float iy10 = s * xb + c * ha, iy11 = s * xb + c * hb;
        float ixmn = fminf(fminf(ix00, ix01), fminf(ix10, ix11)) + 255.5f;
        float iymn = fminf(fminf(iy00, iy01), fminf(iy10, iy11)) + 255.5f;
        float iymx = fmaxf(fmaxf(iy00, iy01), fmaxf(iy10, iy11)) + 255.5f;
        int x_lo = (int)floorf(ixmn) - 1;
        int x_lo4 = x_lo & ~3;
        int y_lo = (int)floorf(iymn) - 1;
        int NY = min((int)floorf(iymx) + 3 - y_lo, NYcap);
        int total4 = NY * NXW;
        int nit = (total4 + 255) >> 8;

        __syncthreads();

        // Async staging (linear LDS dest, conflict-free); partial tail wave
        // uses the predicated manual path.
        {
            const unsigned* pb = padq + (y_lo + PAD) * PW + (x_lo4 + PAD);
            for (int k = 0; k < nit; ++k) {
                int i = (k << 8) + tid;
                if (((k << 8) + (g << 6) + 63) < total4) {
                    unsigned ry = ((unsigned)i * mgc) >> 18;   // i / NXW
                    ASYNC_CP16(pb + 4 * i + stepRow * (int)ry, &tileU[i << 2]);
                } else if (i < total4) {
                    unsigned ry = ((unsigned)i * mgc) >> 18;
                    uint4 val = *(const uint4*)(pb + 4 * i + stepRow * (int)ry);
                    *(uint4*)&tileU[i << 2] = val;
                }
            }
        }
        asm volatile("s_waitcnt vmcnt(0)" ::: "memory");
        __syncthreads();

        if (mode == 0) {
            // ---- mapping A: lane=w, wave g handles h = hc+g, +4, ... -----
            float hh0 = (float)(hc + g) - 255.5f;
            float ixr = fmaf(-s, hh0, cxw) - (float)x_lo4;
            float iyr = fmaf(c, hh0, sxw) - (float)y_lo;
            h2 accp0 = (h2)0.0f;
            h2 accp1 = (h2)0.0f;
            int parity = 0;
            #pragma unroll 8
            for (int h = hc + g; h <= hend; h += 4) {
                float fx = floorf(ixr);
                float fy = floorf(iyr);
                int lx = (int)fx;
                int ly = (int)fy;
                float wx1 = ixr - fx;
                float wy1 = iyr - fy;
                h2 wxs = __builtin_amdgcn_cvt_pkrtz(wx1, wx1);
                h2 wys = __builtin_amdgcn_cvt_pkrtz(wy1, wy1);
                const unsigned* p = tileU + (ly * P + lx);
                const unsigned* q = p + P;
                h2 t00 = __builtin_bit_cast(h2, p[0]);
                h2 t01 = __builtin_bit_cast(h2, p[1]);
                h2 t10 = __builtin_bit_cast(h2, q[0]);
                h2 t11 = __builtin_bit_cast(h2, q[1]);
                h2 r0 = t00 + (t01 - t00) * wxs;
                h2 r1 = t10 + (t11 - t10) * wxs;
                h2 contrib = r0 + (r1 - r0) * wys;
                if (parity) accp1 += contrib; else accp0 += contrib;
                parity ^= 1;
                ixr += step4x;
                iyr += step4y;
            }
            acc0 += (float)accp0.x + (float)accp1.x;
            acc1 += (float)accp0.y + (float)accp1.y;
        } else if (!(wh1 < hc || wh0 > hend)) {
            // ---- mapping B: lane=h (CENTERED coord!), loop over 16 w's ---
            bool vld = (hc + lane) <= hend;
            float hlc = (float)min(hc + lane, hend) - 255.5f;   // <- the fix
            float SL = s * hlc;
            float CL = c * hlc;
            float xwj = (float)(wc * WCHUNK + (g << 4)) + 0.5f - 256.0f;
            float U = fmaf(c, xwj, 255.5f) - (float)x_lo4;
            float V = fmaf(s, xwj, 255.5f) - (float)y_lo;
            #pragma unroll
            for (int j = 0; j < 16; ++j) {
                float ixr = U - SL;
                float iyr = V + CL;
                float fx = floorf(ixr);
                float fy = floorf(iyr);
                int lx = (int)fx;
                int ly = (int)fy;
                float wx1 = ixr - fx;
                float wy1 = iyr - fy;
                h2 wxs = __builtin_amdgcn_cvt_pkrtz(wx1, wx1);
                h2 wys = __builtin_amdgcn_cvt_pkrtz(wy1, wy1);
                const unsigned* p = tileU + (ly * P + lx);
                const unsigned* q = p + P;
                h2 t00 = __builtin_bit_cast(h2, p[0]);
                h2 t01 = __builtin_bit_cast(h2, p[1]);
                h2 t10 = __builtin_bit_cast(h2, q[0]);
                h2 t11 = __builtin_bit_cast(h2, q[1]);
                h2 r0 = t00 + (t01 - t00) * wxs;
                h2 r1 = t10 + (t11 - t10) * wxs;
                h2 contrib = r0 + (r1 - r0) * wys;
                accB[j] += vld ? contrib : (h2)0.0f;
                U += c;
                V += s;
            }
        }
    }

    if (mode == 0) {
        // Reduce the 4 h-phase partials for both batches, reusing the tile.
        __syncthreads();
        tileU[(g << 6) + lane] = __float_as_uint(acc0);
        tileU[256 + (g << 6) + lane] = __float_as_uint(acc1);
        __syncthreads();
        if (g == 0) {
            float r0 = __uint_as_float(tileU[lane]) + __uint_as_float(tileU[64 + lane]) +
                       __uint_as_float(tileU[128 + lane]) + __uint_as_float(tileU[192 + lane]);
            float r1 = __uint_as_float(tileU[256 + lane]) + __uint_as_float(tileU[320 + lane]) +
                       __uint_as_float(tileU[384 + lane]) + __uint_as_float(tileU[448 + lane]);
            size_t o = (size_t)w * VIEWS + v;
            out[o] = r0 * 0.5f;
            out[(size_t)IMGSZ * VIEWS + o] = r1 * 0.5f;
        }
    } else {
        // Mapping B: butterfly-reduce each w over the 64 h-lanes (f32).
        #pragma unroll
        for (int j = 0; j < 16; ++j) {
            float a0 = (float)accB[j].x;
            float a1 = (float)accB[j].y;
            #pragma unroll
            for (int m = 1; m < 64; m <<= 1) {
                a0 += __shfl_xor(a0, m, 64);
                a1 += __shfl_xor(a1, m, 64);
            }
            if (lane == 0) {
                int wj = wc * WCHUNK + (g << 4) + j;
                size_t o = (size_t)wj * VIEWS + v;
                out[o] = a0 * 0.5f;
                out[(size_t)IMGSZ * VIEWS + o] = a1 * 0.5f;
            }
        }
    }
}

extern "C" void kernel_launch(void* const* d_in, const int* in_sizes, int n_in,
                              void* d_out, int out_size, void* d_ws, size_t ws_size,
                              hipStream_t stream) {
    const float* x = (const float*)d_in[0];
    float* out = (float*)d_out;
    unsigned* padq = (unsigned*)d_ws;   // PH*PW*4 = 2,004,992 bytes

    constexpr int padTotal = PH * (PW / 4);          // 125312 groups
    pad_kernel<<<(padTotal + 255) / 256, 256, 0, stream>>>(x, padq);

    int nblocks = VIEWS * (IMGSZ / WCHUNK);          // 2880
    fp_kernel<<<nblocks, 256, 0, stream>>>(padq, out);
}

// Round 4
// 165.754 us; speedup vs baseline: 1.0052x; 1.0052x over previous
//
#include <hip/hip_runtime.h>

typedef __fp16 h2 __attribute__((ext_vector_type(2)));

constexpr int VIEWS = 360;
constexpr int IMGSZ = 512;
constexpr int WCHUNK = 64;   // w per block
constexpr int KH = 40;       // h per LDS chunk (was 64): smaller tile -> 5 blocks/CU
constexpr int NXF4 = 25;     // staged box width in 4-dword groups (100 texels)
constexpr int PITCH = 100;   // dwords (texel positions) per LDS row (compile-time!)
constexpr int MAXNY = 79;    // max staged rows: ceil(sqrt(63^2+39^2))+4 = 79
constexpr int LDSDW = PITCH * MAXNY;   // 7900 dwords = 31600 B; 5 blocks/CU
constexpr int PW = 712;      // padded width (dword positions per row)
constexpr int PH = 704;      // padded height
constexpr int PAD = 96;

// Async global->LDS 16B copy. LDS dest = wave-uniform base + lane*16;
// global src is per-lane.
#define ASYNC_CP16(SRC, DST)                                              \
    __builtin_amdgcn_global_load_lds(                                     \
        (const __attribute__((address_space(1))) unsigned*)(SRC),         \
        (__attribute__((address_space(3))) unsigned*)(DST), 16, 0, 0)

// ---------- pad kernel: zero-padded, BATCH-PACKED f16 texels ---------------
// padq[py][px] = (f16 img_b0[py-PAD][px-PAD], f16 img_b1[py-PAD][px-PAD])
__global__ __launch_bounds__(256) void pad_kernel(const float* __restrict__ x,
                                                  unsigned* __restrict__ padq) {
    constexpr int PW4 = PW / 4;              // 178 groups per row
    constexpr int total = PH * PW4;          // 125312 groups
    int idx = blockIdx.x * 256 + threadIdx.x;
    if (idx >= total) return;
    int py = idx / PW4;
    int px4 = idx - py * PW4;
    int gx = px4 * 4 - PAD;                  // multiple of 4
    int gy = py - PAD;
    const float* img0 = x;
    const float* img1 = x + (size_t)IMGSZ * IMGSZ;
    float4 a = make_float4(0.f, 0.f, 0.f, 0.f);
    float4 bq = a;
    if ((unsigned)gy < (unsigned)IMGSZ && (unsigned)gx < (unsigned)IMGSZ) {
        size_t off = (size_t)gy * IMGSZ + gx;    // gx%4==0 -> all-in/all-out
        a  = *(const float4*)(img0 + off);
        bq = *(const float4*)(img1 + off);
    }
    uint4 d;
    d.x = __builtin_bit_cast(unsigned, __builtin_amdgcn_cvt_pkrtz(a.x, bq.x));
    d.y = __builtin_bit_cast(unsigned, __builtin_amdgcn_cvt_pkrtz(a.y, bq.y));
    d.z = __builtin_bit_cast(unsigned, __builtin_amdgcn_cvt_pkrtz(a.z, bq.z));
    d.w = __builtin_bit_cast(unsigned, __builtin_amdgcn_cvt_pkrtz(a.w, bq.w));
    *(uint4*)&padq[(size_t)idx * 4] = d;
}

// ---------- main kernel: mapping A only, const pitch, 5 blocks/CU ----------
__global__ __launch_bounds__(256) void fp_kernel(const unsigned* __restrict__ padq,
                                                 float* __restrict__ out) {
    __shared__ __align__(16) unsigned tileU[LDSDW];

    int blk = blockIdx.x;          // 2880 = VIEWS * 8
    int wc = blk & 7;
    int v = blk >> 3;

    int tid = threadIdx.x;
    int lane = tid & 63;
    int g = tid >> 6;              // h phase 0..3
    int w = wc * WCHUNK + lane;

    double ang = -3.14159265358979323846 * (double)(v + 1) / (double)VIEWS
                 - 3.14159265358979323846;
    float c = (float)cos(ang);
    float s = (float)sin(ang);

    float xw = (float)w + 0.5f - 256.0f;
    float cxw = fmaf(c, xw, 255.5f);
    float sxw = fmaf(s, xw, 255.5f);

    // Per-thread valid-h interval (identical to validated rounds 0-1).
    float lo = -1e30f, hi = 1e30f;
    {
        float coef = -s, base = cxw;
        if (fabsf(coef) > 1e-6f) {
            float a = (-1.0f - base) / coef;
            float bq = (512.0f - base) / coef;
            lo = fmaxf(lo, fminf(a, bq));
            hi = fminf(hi, fmaxf(a, bq));
        } else if (!(base > -1.0f && base < 512.0f)) {
            lo = 1e30f; hi = -1e30f;
        }
    }
    {
        float coef = c, base = sxw;
        if (fabsf(coef) > 1e-6f) {
            float a = (-1.0f - base) / coef;
            float bq = (512.0f - base) / coef;
            lo = fmaxf(lo, fminf(a, bq));
            hi = fminf(hi, fmaxf(a, bq));
        } else if (!(base > -1.0f && base < 512.0f)) {
            lo = 1e30f; hi = -1e30f;
        }
    }
    float h0f = fminf(fmaxf(floorf(lo + 255.5f) - 1.0f, 0.0f), 512.0f);
    float h1f = fminf(fmaxf(ceilf(hi + 255.5f) + 1.0f, -1.0f), 511.0f);
    int h0 = (int)h0f;
    int h1 = (int)h1f;

    int bh0 = h0, bh1 = h1;
    #pragma unroll
    for (int m = 1; m < 64; m <<= 1) {
        bh0 = min(bh0, __shfl_xor(bh0, m, 64));
        bh1 = max(bh1, __shfl_xor(bh1, m, 64));
    }

    float xa = (float)(wc * WCHUNK) + 0.5f - 256.0f;
    float xb = xa + 63.0f;

    float acc0 = 0.0f, acc1 = 0.0f;
    float step4x = -4.0f * s;
    float step4y = 4.0f * c;

    for (int hc = bh0; hc <= bh1; hc += KH) {
        int hend = min(hc + KH - 1, bh1);

        float ha = (float)hc - 255.5f;
        float hb = (float)hend - 255.5f;
        float ix00 = c * xa - s * ha, ix01 = c * xa - s * hb;
        float ix10 = c * xb - s * ha, ix11 = c * xb - s * hb;
        float iy00 = s * xa + c * ha, iy01 = s * xa + c * hb;
        float iy10 = s * xb + c * ha, iy11 = s * xb + c * hb;
        float ixmn = fminf(fminf(ix00, ix01), fminf(ix10, ix11)) + 255.5f;
        float iymn = fminf(fminf(iy00, iy01), fminf(iy10, iy11)) + 255.5f;
        float iymx = fmaxf(fmaxf(iy00, iy01), fmaxf(iy10, iy11)) + 255.5f;
        int x_lo = (int)floorf(ixmn) - 1;
        int x_lo4 = x_lo & ~3;
        int y_lo = (int)floorf(iymn) - 1;
        int NY = min((int)floorf(iymx) + 3 - y_lo, MAXNY);
        int total4 = NY * NXF4;            // <= 1975
        int nit = (total4 + 255) >> 8;     // <= 8

        __syncthreads();

        // Async staging (linear LDS dest); partial tail wave uses the
        // predicated manual path. Division by NXF4=25 is const magic-mul.
        {
            const unsigned* pb = padq + (y_lo + PAD) * PW + (x_lo4 + PAD);
            for (int k = 0; k < nit; ++k) {
                int i = (k << 8) + tid;
                if (((k << 8) + (g << 6) + 63) < total4) {
                    int ry = i / NXF4;
                    ASYNC_CP16(pb + 4 * i + (PW - 4 * NXF4) * ry, &tileU[i << 2]);
                } else if (i < total4) {
                    int ry = i / NXF4;
                    uint4 val = *(const uint4*)(pb + 4 * i + (PW - 4 * NXF4) * ry);
                    *(uint4*)&tileU[i << 2] = val;
                }
            }
        }
        asm volatile("s_waitcnt vmcnt(0)" ::: "memory");
        __syncthreads();

        // Gather: 2 x ds_read2_b32 per sample; packed-f16 lerp serves both
        // batches at once. Wave g handles h = hc+g, +4, ...
        float hh0 = (float)(hc + g) - 255.5f;
        float ixr = fmaf(-s, hh0, cxw) - (float)x_lo4;
        float iyr = fmaf(c, hh0, sxw) - (float)y_lo;
        h2 accp0 = (h2)0.0f;
        h2 accp1 = (h2)0.0f;
        int parity = 0;
        #pragma unroll 8
        for (int h = hc + g; h <= hend; h += 4) {
            float fx = floorf(ixr);
            float fy = floorf(iyr);
            int lx = (int)fx;
            int ly = (int)fy;
            float wx1 = ixr - fx;
            float wy1 = iyr - fy;
            h2 wxs = __builtin_amdgcn_cvt_pkrtz(wx1, wx1);
            h2 wys = __builtin_amdgcn_cvt_pkrtz(wy1, wy1);
            const unsigned* p = tileU + (ly * PITCH + lx);
            h2 t00 = __builtin_bit_cast(h2, p[0]);
            h2 t01 = __builtin_bit_cast(h2, p[1]);
            h2 t10 = __builtin_bit_cast(h2, p[PITCH]);
            h2 t11 = __builtin_bit_cast(h2, p[PITCH + 1]);
            h2 r0 = t00 + (t01 - t00) * wxs;
            h2 r1 = t10 + (t11 - t10) * wxs;
            h2 contrib = r0 + (r1 - r0) * wys;
            if (parity) accp1 += contrib; else accp0 += contrib;
            parity ^= 1;
            ixr += step4x;
            iyr += step4y;
        }
        acc0 += (float)accp0.x + (float)accp1.x;
        acc1 += (float)accp0.y + (float)accp1.y;
    }

    // Reduce the 4 h-phase partials for both batches, reusing the tile.
    __syncthreads();
    tileU[(g << 6) + lane] = __float_as_uint(acc0);
    tileU[256 + (g << 6) + lane] = __float_as_uint(acc1);
    __syncthreads();
    if (g == 0) {
        float r0 = __uint_as_float(tileU[lane]) + __uint_as_float(tileU[64 + lane]) +
                   __uint_as_float(tileU[128 + lane]) + __uint_as_float(tileU[192 + lane]);
        float r1 = __uint_as_float(tileU[256 + lane]) + __uint_as_float(tileU[320 + lane]) +
                   __uint_as_float(tileU[384 + lane]) + __uint_as_float(tileU[448 + lane]);
        size_t o = (size_t)w * VIEWS + v;
        out[o] = r0 * 0.5f;
        out[(size_t)IMGSZ * VIEWS + o] = r1 * 0.5f;
    }
}

extern "C" void kernel_launch(void* const* d_in, const int* in_sizes, int n_in,
                              void* d_out, int out_size, void* d_ws, size_t ws_size,
                              hipStream_t stream) {
    const float* x = (const float*)d_in[0];
    float* out = (float*)d_out;
    unsigned* padq = (unsigned*)d_ws;   // PH*PW*4 = 2,004,992 bytes

    constexpr int padTotal = PH * (PW / 4);          // 125312 groups
    pad_kernel<<<(padTotal + 255) / 256, 256, 0, stream>>>(x, padq);

    int nblocks = VIEWS * (IMGSZ / WCHUNK);          // 2880
    fp_kernel<<<nblocks, 256, 0, stream>>>(padq, out);
}